// Round 4
// baseline (27.430 us; speedup 1.0000x reference)
//
#include <hip/hip_runtime.h>
#include <stdint.h>

#define BATCH 16384
#define KDIM  512
#define NDIM  1024
#define NW    16            // 512 bits = 16 uint32 words per row
#define THREADS 512         // 8 waves; each thread owns 2 adjacent columns
#define ROWS_PER_BLOCK 16   // 1024 blocks
#define PHASE_ROWS 4        // one float4/thread = 4 rows per phase
#define NPHASE (ROWS_PER_BLOCK / PHASE_ROWS)

// --- G packing (UNCHANGED — verified correct in rounds 2-3) ---
// Word m (0..15) of a packed K-row, bit c (0..31) corresponds to
//   k = 256*(m>>3) + 128*((m>>2)&1) + 4*c + (m&3)
__global__ __launch_bounds__(256) void pack_g_kernel(const float* __restrict__ G,
                                                     uint32_t* __restrict__ Gt) {
    int t = blockIdx.x * 256 + threadIdx.x;   // 16384 threads: t = m*NDIM + n
    int n = t & (NDIM - 1);
    int m = t >> 10;
    int kbase = 256 * (m >> 3) + 128 * ((m >> 2) & 1) + (m & 3);
    uint32_t w = 0;
#pragma unroll
    for (int c = 0; c < 32; ++c) {
        w |= (uint32_t)(G[(size_t)(kbase + 4 * c) * NDIM + n] > 0.5f) << c;
    }
    Gt[t] = w;
}

// --- fused pack(x) + GF(2) GEMM, 2 columns/thread ---
// 512 threads (8 waves). Thread owns cols {2*tid, 2*tid+1}: g[2][16] = 32 VGPRs.
// Per phase: one float4/thread covers 4 rows; wave w (q=w>>1, h=w&1) ballots
// its 256 floats of row q into 8 words; lane 0 deposits to LDS (double-buffered,
// one barrier per phase). Compute amortizes each row's 4 ds_read_b128 over 2
// output columns: out = popc(XOR_m (xrow[m] & g[m])) & 1, stored as int2.
__global__ __launch_bounds__(THREADS, 6)
void gf2_fused_kernel(const float* __restrict__ x,
                      const uint32_t* __restrict__ Gt,
                      int* __restrict__ out) {
    const int tid = threadIdx.x;
    const int w   = tid >> 6;     // wave 0..7
    const int l   = tid & 63;     // lane
    const int q   = w >> 1;       // row within phase (0..3)
    const int h   = w & 1;        // k-half (0: k<256, 1: k>=256)
    const int row0 = blockIdx.x * ROWS_PER_BLOCK;

    // persistent column fragments: cols 2*tid, 2*tid+1 (coalesced uint2 loads)
    uint32_t g0[NW], g1[NW];
#pragma unroll
    for (int m = 0; m < NW; ++m) {
        uint2 gg = reinterpret_cast<const uint2*>(Gt + m * NDIM)[tid];
        g0[m] = gg.x;
        g1[m] = gg.y;
    }

    __shared__ __align__(16) uint32_t xw[2][PHASE_ROWS][NW];   // 2 x 256 B

    const float4* xf = reinterpret_cast<const float4*>(x);
    float4 f = xf[(size_t)row0 * (KDIM / 4) + tid];            // phase-0 slab

    for (int p = 0; p < NPHASE; ++p) {
        // ---- ballot-pack 4 rows (consumes f) ----
        uint64_t b0 = __ballot(f.x > 0.5f);
        uint64_t b1 = __ballot(f.y > 0.5f);
        uint64_t b2 = __ballot(f.z > 0.5f);
        uint64_t b3 = __ballot(f.w > 0.5f);

        // prefetch next phase's slab (hidden under compute below)
        if (p + 1 < NPHASE)
            f = xf[(size_t)(row0 + (p + 1) * PHASE_ROWS) * (KDIM / 4) + tid];

        if (l == 0) {
            uint32_t* dst = &xw[p & 1][q][h * 8];
            dst[0] = (uint32_t)b0;  dst[4] = (uint32_t)(b0 >> 32);
            dst[1] = (uint32_t)b1;  dst[5] = (uint32_t)(b1 >> 32);
            dst[2] = (uint32_t)b2;  dst[6] = (uint32_t)(b2 >> 32);
            dst[3] = (uint32_t)b3;  dst[7] = (uint32_t)(b3 >> 32);
        }
        __syncthreads();   // double-buffer: one barrier per phase is race-free

        // ---- compute 4 rows x 2 columns ----
        size_t obase = (size_t)(row0 + p * PHASE_ROWS) * NDIM + 2 * (size_t)tid;
#pragma unroll
        for (int r = 0; r < PHASE_ROWS; ++r) {
            const uint4* x4 = reinterpret_cast<const uint4*>(&xw[p & 1][r][0]);
            uint4 a0 = x4[0], a1 = x4[1], a2 = x4[2], a3 = x4[3];
            uint32_t t0 = (a0.x & g0[0])  ^ (a0.y & g0[1])  ^ (a0.z & g0[2])  ^ (a0.w & g0[3])
                        ^ (a1.x & g0[4])  ^ (a1.y & g0[5])  ^ (a1.z & g0[6])  ^ (a1.w & g0[7])
                        ^ (a2.x & g0[8])  ^ (a2.y & g0[9])  ^ (a2.z & g0[10]) ^ (a2.w & g0[11])
                        ^ (a3.x & g0[12]) ^ (a3.y & g0[13]) ^ (a3.z & g0[14]) ^ (a3.w & g0[15]);
            uint32_t t1 = (a0.x & g1[0])  ^ (a0.y & g1[1])  ^ (a0.z & g1[2])  ^ (a0.w & g1[3])
                        ^ (a1.x & g1[4])  ^ (a1.y & g1[5])  ^ (a1.z & g1[6])  ^ (a1.w & g1[7])
                        ^ (a2.x & g1[8])  ^ (a2.y & g1[9])  ^ (a2.z & g1[10]) ^ (a2.w & g1[11])
                        ^ (a3.x & g1[12]) ^ (a3.y & g1[13]) ^ (a3.z & g1[14]) ^ (a3.w & g1[15]);
            int2 o;
            o.x = (int)(__popc(t0) & 1u);
            o.y = (int)(__popc(t1) & 1u);
            *reinterpret_cast<int2*>(out + obase + (size_t)r * NDIM) = o;
        }
    }
}

extern "C" void kernel_launch(void* const* d_in, const int* in_sizes, int n_in,
                              void* d_out, int out_size, void* d_ws, size_t ws_size,
                              hipStream_t stream) {
    const float* x = (const float*)d_in[0];   // [BATCH, KDIM] float32 (0/1)
    const float* G = (const float*)d_in[1];   // [KDIM, NDIM] float32 (0/1)
    int* out = (int*)d_out;                   // [BATCH, NDIM] int32

    uint32_t* Gt = (uint32_t*)d_ws;           // 64 KiB packed G

    pack_g_kernel<<<(NW * NDIM) / 256, 256, 0, stream>>>(G, Gt);
    gf2_fused_kernel<<<BATCH / ROWS_PER_BLOCK, THREADS, 0, stream>>>(x, Gt, out);
}